// Round 2
// baseline (535.794 us; speedup 1.0000x reference)
//
#include <hip/hip_runtime.h>

// ---------------------------------------------------------------------------
// AttentionLayer_Spa — MI355X bf16-MFMA pipeline
//   B=4 T=12 N=1024 C=128 D=512 H=8 hd=64 S=60, BT=48
// Pipeline: cvt_w, cvt_x, pool_x, G1(qev), G2(kv), EZ(Z), ES(stats),
//           ATT(fused attn+ext), G3(out proj, fp32)
// R1 fix: cvt_x grid 49152 -> 24576 (was reading 100MB past x: 1 float4/thread,
//         6,291,456 float4s total). aout aliases xb (dead after G1): ws 270->220MB.
// ---------------------------------------------------------------------------

#define LOG2E 1.44269504088896f

typedef __attribute__((ext_vector_type(4))) float f32x4;
typedef __attribute__((ext_vector_type(8))) short bf16x8;

__device__ __forceinline__ unsigned short f2bf(float f) {
    union { float f; unsigned u; } v; v.f = f;
    unsigned r = (v.u + 0x7fffu + ((v.u >> 16) & 1u)) >> 16;
    return (unsigned short)r;
}
__device__ __forceinline__ float bf2f(unsigned short h) {
    union { unsigned u; float f; } v; v.u = ((unsigned)h) << 16;
    return v.f;
}

// ---------------------------------------------------------------------------
// K0a: weight/bias conversion.
//  Wqe (1024x512 bf16) = [Wq; We], Wkv = [Wk; Wv], Wob (512x512 bf16)
//  U1T (64x64 bf16): U1T[s][k] = U1[k][s] (s>=60 -> 0)
//  U2bT(64x64 bf16): U2bT[d][s] = U2[s][d]*0.5 (s>=60 -> 0)
//  bqe (1024 f32) = [bq; be], bkv = [bk; bv]
// total threads = 1,320,960 = 5160*256 exactly
// ---------------------------------------------------------------------------
__global__ void cvt_w(const float* __restrict__ Wq, const float* __restrict__ Wk,
                      const float* __restrict__ Wv, const float* __restrict__ We,
                      const float* __restrict__ Wo, const float* __restrict__ U1,
                      const float* __restrict__ U2,
                      const float* __restrict__ bq, const float* __restrict__ bk,
                      const float* __restrict__ bv, const float* __restrict__ be,
                      unsigned short* __restrict__ Wqe, unsigned short* __restrict__ Wkv,
                      unsigned short* __restrict__ Wob, unsigned short* __restrict__ U1T,
                      unsigned short* __restrict__ U2bT,
                      float* __restrict__ bqe, float* __restrict__ bkv)
{
    int i = blockIdx.x * 256 + threadIdx.x;
    if (i < 524288) {
        int r = i >> 9;
        float v = (r < 512) ? Wq[i] : We[i - 262144];
        Wqe[i] = f2bf(v);
    } else if (i < 1048576) {
        int j = i - 524288; int r = j >> 9;
        float v = (r < 512) ? Wk[j] : Wv[j - 262144];
        Wkv[j] = f2bf(v);
    } else if (i < 1310720) {
        int j = i - 1048576;
        Wob[j] = f2bf(Wo[j]);
    } else if (i < 1314816) {
        int j = i - 1310720; int s = j >> 6, k = j & 63;
        U1T[j] = (s < 60) ? f2bf(U1[k * 60 + s]) : (unsigned short)0;
    } else if (i < 1318912) {
        int j = i - 1314816; int d = j >> 6, s = j & 63;
        U2bT[j] = (s < 60) ? f2bf(U2[s * 64 + d] * 0.5f) : (unsigned short)0;
    } else if (i < 1319936) {
        int j = i - 1318912;
        bqe[j] = (j < 512) ? bq[j] : be[j - 512];
    } else if (i < 1320960) {
        int j = i - 1319936;
        bkv[j] = (j < 512) ? bk[j] : bv[j - 512];
    }
}

// ---------------------------------------------------------------------------
// K0b: x fp32 -> bf16.  25,165,824 elements = 6,291,456 float4, 1/thread.
// grid = 24576 blocks x 256.
// ---------------------------------------------------------------------------
__global__ void cvt_x(const float* __restrict__ x, unsigned short* __restrict__ xb)
{
    long i = (long)blockIdx.x * 256 + threadIdx.x;
    float4 v = ((const float4*)x)[i];
    ushort4 o;
    o.x = f2bf(v.x); o.y = f2bf(v.y); o.z = f2bf(v.z); o.w = f2bf(v.w);
    ((ushort4*)xb)[i] = o;
}

// ---------------------------------------------------------------------------
// K0c: pooled x -> bf16.  xp[bt,c,d] = mean_{j<8} x[bt,c*8+j,d].
// 786432 threads (4 d per thread). grid = 3072.
// ---------------------------------------------------------------------------
__global__ void pool_x(const float* __restrict__ x, unsigned short* __restrict__ xpb)
{
    int i = blockIdx.x * 256 + threadIdx.x;   // < 786432
    int d4 = i & 127;                          // float4 index within row
    int btc = i >> 7;                          // bt*128 + c
    int bt = btc >> 7, c = btc & 127;
    const float4* src = (const float4*)x + ((long)(bt * 1024 + c * 8)) * 128 + d4;
    float sx = 0.f, sy = 0.f, sz = 0.f, sw = 0.f;
#pragma unroll
    for (int j = 0; j < 8; j++) {
        float4 v = src[(long)j * 128];
        sx += v.x; sy += v.y; sz += v.z; sw += v.w;
    }
    ushort4 o;
    o.x = f2bf(sx * 0.125f); o.y = f2bf(sy * 0.125f);
    o.z = f2bf(sz * 0.125f); o.w = f2bf(sw * 0.125f);
    ((ushort4*)xpb)[(long)btc * 128 + d4] = o;
}

// ---------------------------------------------------------------------------
// GEMM: C(MxN) = A(MxK) @ W(NxK)^T + bias[N].  bf16 in, bf16 or fp32 out.
// 128x128 tile, BK=32, 4 waves (2x2 of 64x64), 16x16x32 bf16 MFMA.
// ---------------------------------------------------------------------------
template <int OUTF32>
__global__ __launch_bounds__(256, 2) void gemm_bt(
    const unsigned short* __restrict__ A, const unsigned short* __restrict__ W,
    const float* __restrict__ bias, void* __restrict__ Cout,
    int M, int N, int K)
{
    __shared__ __attribute__((aligned(16))) unsigned short As[128 * 32];
    __shared__ __attribute__((aligned(16))) unsigned short Bs[128 * 32];
    const int tid = threadIdx.x;
    const int wave = tid >> 6, lane = tid & 63;
    const int quad = lane >> 4, l16 = lane & 15;
    const int m0 = blockIdx.x * 128, n0 = blockIdx.y * 128;
    const int wm = (wave & 1) * 64, wn = (wave >> 1) * 64;

    f32x4 acc[4][4];
#pragma unroll
    for (int i = 0; i < 4; i++)
#pragma unroll
        for (int j = 0; j < 4; j++) acc[i][j] = (f32x4){0.f, 0.f, 0.f, 0.f};

    const int c0 = tid, c1 = tid + 256;                  // 512 16B-chunks per tile
    const int r0 = c0 >> 2, kc0 = (c0 & 3) * 8;
    const int r1 = c1 >> 2, kc1 = (c1 & 3) * 8;

    for (int k0 = 0; k0 < K; k0 += 32) {
        int4 a0 = *(const int4*)(A + (long)(m0 + r0) * K + k0 + kc0);
        int4 a1 = *(const int4*)(A + (long)(m0 + r1) * K + k0 + kc1);
        int4 b0 = *(const int4*)(W + (long)(n0 + r0) * K + k0 + kc0);
        int4 b1 = *(const int4*)(W + (long)(n0 + r1) * K + k0 + kc1);
        __syncthreads();
        *(int4*)&As[c0 * 8] = a0; *(int4*)&As[c1 * 8] = a1;
        *(int4*)&Bs[c0 * 8] = b0; *(int4*)&Bs[c1 * 8] = b1;
        __syncthreads();
        bf16x8 af[4], bfr[4];
#pragma unroll
        for (int t = 0; t < 4; t++)
            af[t] = *(const bf16x8*)&As[(wm + t * 16 + l16) * 32 + quad * 8];
#pragma unroll
        for (int t = 0; t < 4; t++)
            bfr[t] = *(const bf16x8*)&Bs[(wn + t * 16 + l16) * 32 + quad * 8];
#pragma unroll
        for (int tm = 0; tm < 4; tm++)
#pragma unroll
            for (int tn = 0; tn < 4; tn++)
                acc[tm][tn] = __builtin_amdgcn_mfma_f32_16x16x32_bf16(
                    af[tm], bfr[tn], acc[tm][tn], 0, 0, 0);
    }

#pragma unroll
    for (int tm = 0; tm < 4; tm++)
#pragma unroll
        for (int tn = 0; tn < 4; tn++) {
            int cc = n0 + wn + tn * 16 + l16;
            float bv = bias[cc];
#pragma unroll
            for (int r = 0; r < 4; r++) {
                int rr = m0 + wm + tm * 16 + quad * 4 + r;
                float v = acc[tm][tn][r] + bv;
                if (OUTF32) ((float*)Cout)[(long)rr * N + cc] = v;
                else        ((unsigned short*)Cout)[(long)rr * N + cc] = f2bf(v);
            }
        }
}

// ---------------------------------------------------------------------------
// EZ: Z[(bt*8+h)*1024+n][s] = ev[bt,n,h*64:...] @ U1  (bf16 out, s<60)
// block = (bt,h,nb): 128 rows x 64 cols (60 valid), K=64. grid = 3072.
// ---------------------------------------------------------------------------
__global__ __launch_bounds__(256, 2) void ez_kernel(
    const unsigned short* __restrict__ qev, const unsigned short* __restrict__ U1T,
    unsigned short* __restrict__ Z)
{
    __shared__ __attribute__((aligned(16))) unsigned short evs[128 * 72];
    __shared__ __attribute__((aligned(16))) unsigned short u1s[64 * 72];
    int tid = threadIdx.x, bx = blockIdx.x;
    int bt = bx >> 6, h = (bx >> 3) & 7, nb = bx & 7;
    int wave = tid >> 6, lane = tid & 63, quad = lane >> 4, l16 = lane & 15;

#pragma unroll
    for (int i = 0; i < 4; i++) {
        int c = tid + i * 256; int row = c >> 3, kc = (c & 7) * 8;
        *(int4*)&evs[row * 72 + kc] =
            *(const int4*)(qev + ((long)(bt * 1024 + nb * 128 + row)) * 1024 + 512 + h * 64 + kc);
    }
#pragma unroll
    for (int i = 0; i < 2; i++) {
        int c = tid + i * 256; int row = c >> 3, kc = (c & 7) * 8;
        *(int4*)&u1s[row * 72 + kc] = *(const int4*)(U1T + row * 64 + kc);
    }
    __syncthreads();

    f32x4 acc[2][4];
#pragma unroll
    for (int i = 0; i < 2; i++)
#pragma unroll
        for (int t = 0; t < 4; t++) acc[i][t] = (f32x4){0.f, 0.f, 0.f, 0.f};

#pragma unroll
    for (int kt = 0; kt < 2; kt++) {
        bf16x8 a[2], b[4];
#pragma unroll
        for (int i = 0; i < 2; i++)
            a[i] = *(const bf16x8*)&evs[((wave * 2 + i) * 16 + l16) * 72 + kt * 32 + quad * 8];
#pragma unroll
        for (int t = 0; t < 4; t++)
            b[t] = *(const bf16x8*)&u1s[(t * 16 + l16) * 72 + kt * 32 + quad * 8];
#pragma unroll
        for (int i = 0; i < 2; i++)
#pragma unroll
            for (int t = 0; t < 4; t++)
                acc[i][t] = __builtin_amdgcn_mfma_f32_16x16x32_bf16(a[i], b[t], acc[i][t], 0, 0, 0);
    }

    long zb = (long)(bt * 8 + h) * 1024 + nb * 128;
#pragma unroll
    for (int i = 0; i < 2; i++)
#pragma unroll
        for (int t = 0; t < 4; t++) {
            int s = t * 16 + l16;
            if (s < 60) {
#pragma unroll
                for (int r = 0; r < 4; r++) {
                    int rr = (wave * 2 + i) * 16 + quad * 4 + r;
                    Z[(zb + rr) * 60 + s] = f2bf(acc[i][t][r]);
                }
            }
        }
}

// ---------------------------------------------------------------------------
// ES: per (bt,h): column softmax stats over n=0..1023 for s=0..59.
//   mS = max_n Z, lSinv = 1/sum_n exp(Z - mS). grid = 384.
// ---------------------------------------------------------------------------
__global__ __launch_bounds__(256, 2) void es_kernel(
    const unsigned short* __restrict__ Z, float* __restrict__ mS, float* __restrict__ lSinv)
{
    __shared__ float ms[4][64];
    __shared__ float ls[4][64];
    int tid = threadIdx.x;
    int s = tid & 63, g = tid >> 6;
    long zb = (long)blockIdx.x * 1024 * 60;
    float m = -1e30f, l = 0.f;
    if (s < 60) {
        for (int r = 0; r < 256; r++) {
            float z = bf2f(Z[zb + (long)(g * 256 + r) * 60 + s]);
            float nm = fmaxf(m, z);
            l = l * exp2f((m - nm) * LOG2E) + exp2f((z - nm) * LOG2E);
            m = nm;
        }
    }
    ms[g][s] = m; ls[g][s] = l;
    __syncthreads();
    if (tid < 60) {
        float M = fmaxf(fmaxf(ms[0][tid], ms[1][tid]), fmaxf(ms[2][tid], ms[3][tid]));
        float L = 0.f;
#pragma unroll
        for (int gg = 0; gg < 4; gg++) L += ls[gg][tid] * exp2f((ms[gg][tid] - M) * LOG2E);
        mS[blockIdx.x * 60 + tid] = M;
        lSinv[blockIdx.x * 60 + tid] = 1.0f / L;
    }
}

// ---------------------------------------------------------------------------
// ATT: per (bt,h,nb): 128 q-rows.
//   S = qh @ kh^T / 8 + adp -> softmax(C=128) -> P
//   out = P @ vh + exa @ U2b + ev;  exa from Z/mS/lSinv.
// grid = 3072, 256 threads, LDS ~78.5 KB -> 2 blocks/CU.
// ---------------------------------------------------------------------------
__global__ __launch_bounds__(256, 2) void att_kernel(
    const unsigned short* __restrict__ qev, const unsigned short* __restrict__ kv,
    const unsigned short* __restrict__ Z, const float* __restrict__ mS,
    const float* __restrict__ lSinv, const float* __restrict__ adp,
    const unsigned short* __restrict__ U2bT, unsigned short* __restrict__ attn_out)
{
    __shared__ __attribute__((aligned(16))) unsigned short khs[128 * 72]; // -> exa later
    __shared__ __attribute__((aligned(16))) unsigned short vts[64 * 136];
    __shared__ __attribute__((aligned(16))) unsigned short Ps[128 * 136];
    __shared__ __attribute__((aligned(16))) unsigned short u2s[64 * 72];
    __shared__ float mSs[64];
    __shared__ float lIs[64];

    int tid = threadIdx.x, bx = blockIdx.x;
    int bt = bx >> 6, h = (bx >> 3) & 7, nb = bx & 7;
    int wave = tid >> 6, lane = tid & 63, quad = lane >> 4, l16 = lane & 15;
    int n0 = nb * 128;
    const long kvrow = (long)bt * 128;
    const long qrow0 = (long)bt * 1024 + n0;

    // --- stage kh, vh^T, U2bT, stats ---
#pragma unroll
    for (int i = 0; i < 4; i++) {
        int c = tid + i * 256; int row = c >> 3, kc = (c & 7) * 8;
        *(int4*)&khs[row * 72 + kc] = *(const int4*)(kv + (kvrow + row) * 1024 + h * 64 + kc);
    }
#pragma unroll
    for (int i = 0; i < 4; i++) {
        int c = tid + i * 256; int row = c >> 3, dc = (c & 7) * 8;
        int4 v = *(const int4*)(kv + (kvrow + row) * 1024 + 512 + h * 64 + dc);
        unsigned short* pv = (unsigned short*)&v;
#pragma unroll
        for (int j = 0; j < 8; j++) vts[(dc + j) * 136 + row] = pv[j];
    }
#pragma unroll
    for (int i = 0; i < 2; i++) {
        int c = tid + i * 256; int row = c >> 3, kc = (c & 7) * 8;
        *(int4*)&u2s[row * 72 + kc] = *(const int4*)(U2bT + row * 64 + kc);
    }
    if (tid < 60) {
        mSs[tid] = mS[(bt * 8 + h) * 60 + tid];
        lIs[tid] = lSinv[(bt * 8 + h) * 60 + tid];
    }
    __syncthreads();

    // --- score: rows (wave*2 + i)*16 .. , all 128 cols ---
    f32x4 sc[2][8];
#pragma unroll
    for (int i = 0; i < 2; i++)
#pragma unroll
        for (int t = 0; t < 8; t++) sc[i][t] = (f32x4){0.f, 0.f, 0.f, 0.f};

#pragma unroll
    for (int kt = 0; kt < 2; kt++) {
        bf16x8 a[2];
#pragma unroll
        for (int i = 0; i < 2; i++)
            a[i] = *(const bf16x8*)(qev + (qrow0 + (wave * 2 + i) * 16 + l16) * 1024
                                    + h * 64 + kt * 32 + quad * 8);
#pragma unroll
        for (int tn = 0; tn < 8; tn++) {
            bf16x8 b = *(const bf16x8*)&khs[(tn * 16 + l16) * 72 + kt * 32 + quad * 8];
#pragma unroll
            for (int i = 0; i < 2; i++)
                sc[i][tn] = __builtin_amdgcn_mfma_f32_16x16x32_bf16(a[i], b, sc[i][tn], 0, 0, 0);
        }
    }

    // --- softmax over 128 cols (spread over 8 tn-regs x 16 lanes) ---
#pragma unroll
    for (int i = 0; i < 2; i++) {
#pragma unroll
        for (int tn = 0; tn < 8; tn++)
#pragma unroll
            for (int r = 0; r < 4; r++) {
                int rr = (wave * 2 + i) * 16 + quad * 4 + r;
                sc[i][tn][r] = sc[i][tn][r] * 0.125f + adp[(n0 + rr) * 128 + tn * 16 + l16];
            }
        float rmax[4], rsum[4];
#pragma unroll
        for (int r = 0; r < 4; r++) {
            float m = sc[i][0][r];
#pragma unroll
            for (int tn = 1; tn < 8; tn++) m = fmaxf(m, sc[i][tn][r]);
#pragma unroll
            for (int d = 1; d < 16; d <<= 1) m = fmaxf(m, __shfl_xor(m, d, 64));
            rmax[r] = m; rsum[r] = 0.f;
        }
#pragma unroll
        for (int tn = 0; tn < 8; tn++)
#pragma unroll
            for (int r = 0; r < 4; r++) {
                float p = exp2f((sc[i][tn][r] - rmax[r]) * LOG2E);
                sc[i][tn][r] = p; rsum[r] += p;
            }
#pragma unroll
        for (int r = 0; r < 4; r++) {
#pragma unroll
            for (int d = 1; d < 16; d <<= 1) rsum[r] += __shfl_xor(rsum[r], d, 64);
            rsum[r] = 1.0f / rsum[r];
        }
#pragma unroll
        for (int tn = 0; tn < 8; tn++)
#pragma unroll
            for (int r = 0; r < 4; r++) {
                int rr = (wave * 2 + i) * 16 + quad * 4 + r;
                Ps[rr * 136 + tn * 16 + l16] = f2bf(sc[i][tn][r] * rsum[r]);
            }
    }
    __syncthreads();   // score reads of khs done; Ps visible

    // --- exa into khs region (aliased) ---
    unsigned short* exs = khs;
    const long zrow0 = (long)(bt * 8 + h) * 1024 + n0;
#pragma unroll
    for (int it = 0; it < 32; it++) {
        int idx = tid + it * 256;            // < 8192
        int rr = idx >> 6, s = idx & 63;
        unsigned short o = 0;
        if (s < 60) {
            float z = bf2f(Z[(zrow0 + rr) * 60 + s]);
            o = f2bf(exp2f((z - mSs[s]) * LOG2E) * lIs[s]);
        }
        exs[rr * 72 + s] = o;
    }
    __syncthreads();

    // --- out = P @ vh + exa @ U2b ---
    f32x4 oc[2][4];
#pragma unroll
    for (int i = 0; i < 2; i++)
#pragma unroll
        for (int t = 0; t < 4; t++) oc[i][t] = (f32x4){0.f, 0.f, 0.f, 0.f};

#pragma unroll
    for (int kt = 0; kt < 4; kt++) {
        bf16x8 a[2];
#pragma unroll
        for (int i = 0; i < 2; i++)
            a[i] = *(const bf16x8*)&Ps[((wave * 2 + i) * 16 + l16) * 136 + kt * 32 + quad * 8];
#pragma unroll
        for (int tn = 0; tn < 4; tn++) {
            bf16x8 b = *(const bf16x8*)&vts[(tn * 16 + l16) * 136 + kt * 32 + quad * 8];
#pragma unroll
            for (int i = 0; i < 2; i++)
                oc[i][tn] = __builtin_amdgcn_mfma_f32_16x16x32_bf16(a[i], b, oc[i][tn], 0, 0, 0);
        }
    }
#pragma unroll
    for (int kt = 0; kt < 2; kt++) {
        bf16x8 a[2];
#pragma unroll
        for (int i = 0; i < 2; i++)
            a[i] = *(const bf16x8*)&exs[((wave * 2 + i) * 16 + l16) * 72 + kt * 32 + quad * 8];
#pragma unroll
        for (int tn = 0; tn < 4; tn++) {
            bf16x8 b = *(const bf16x8*)&u2s[(tn * 16 + l16) * 72 + kt * 32 + quad * 8];
#pragma unroll
            for (int i = 0; i < 2; i++)
                oc[i][tn] = __builtin_amdgcn_mfma_f32_16x16x32_bf16(a[i], b, oc[i][tn], 0, 0, 0);
        }
    }

    // --- epilogue: + ev, write merged-head attn_out (bf16) ---
#pragma unroll
    for (int i = 0; i < 2; i++)
#pragma unroll
        for (int tn = 0; tn < 4; tn++)
#pragma unroll
            for (int r = 0; r < 4; r++) {
                int rr = (wave * 2 + i) * 16 + quad * 4 + r;
                int cc = tn * 16 + l16;
                float ev = bf2f(qev[(qrow0 + rr) * 1024 + 512 + h * 64 + cc]);
                attn_out[(qrow0 + rr) * 512 + h * 64 + cc] = f2bf(oc[i][tn][r] + ev);
            }
}

// ---------------------------------------------------------------------------
// launch
// ---------------------------------------------------------------------------
extern "C" void kernel_launch(void* const* d_in, const int* in_sizes, int n_in,
                              void* d_out, int out_size, void* d_ws, size_t ws_size,
                              hipStream_t stream)
{
    const float* x   = (const float*)d_in[0];
    const float* Wq  = (const float*)d_in[1];
    const float* bq  = (const float*)d_in[2];
    const float* Wk  = (const float*)d_in[3];
    const float* bk  = (const float*)d_in[4];
    const float* Wv  = (const float*)d_in[5];
    const float* bv  = (const float*)d_in[6];
    const float* We  = (const float*)d_in[7];
    const float* be  = (const float*)d_in[8];
    const float* Wo  = (const float*)d_in[9];
    const float* bo  = (const float*)d_in[10];
    const float* adp = (const float*)d_in[11];
    const float* U1  = (const float*)d_in[12];
    const float* U2  = (const float*)d_in[13];

    char* ws = (char*)d_ws;
    unsigned short* xb   = (unsigned short*)(ws + 0);          // 50,331,648 B
    unsigned short* aout = xb;                                 // alias: xb dead after G1
    unsigned short* xpb  = (unsigned short*)(ws + 50331648);   //  6,291,456
    unsigned short* qev  = (unsigned short*)(ws + 56623104);   // 100,663,296
    unsigned short* kvb  = (unsigned short*)(ws + 157286400);  // 12,582,912
    unsigned short* Zb   = (unsigned short*)(ws + 169869312);  // 47,185,920
    unsigned short* Wqe  = (unsigned short*)(ws + 217055232);  //  1,048,576
    unsigned short* Wkv  = (unsigned short*)(ws + 218103808);  //  1,048,576
    unsigned short* Wob  = (unsigned short*)(ws + 219152384);  //    524,288
    unsigned short* U1T  = (unsigned short*)(ws + 219676672);  //      8,192
    unsigned short* U2bT = (unsigned short*)(ws + 219684864);  //      8,192
    float*          bqe  = (float*)(ws + 219693056);           //      4,096
    float*          bkv  = (float*)(ws + 219697152);           //      4,096
    float*          mSb  = (float*)(ws + 219701248);           //     92,160
    float*          lIb  = (float*)(ws + 219793408);           //     92,160
    // total: 219,885,568 B

    cvt_w<<<5160, 256, 0, stream>>>(Wq, Wk, Wv, We, Wo, U1, U2, bq, bk, bv, be,
                                    Wqe, Wkv, Wob, U1T, U2bT, bqe, bkv);
    cvt_x<<<24576, 256, 0, stream>>>(x, xb);
    pool_x<<<3072, 256, 0, stream>>>(x, xpb);

    gemm_bt<0><<<dim3(384, 8), 256, 0, stream>>>(xb,  Wqe, bqe, (void*)qev, 49152, 1024, 512);
    gemm_bt<0><<<dim3(48, 8),  256, 0, stream>>>(xpb, Wkv, bkv, (void*)kvb,  6144, 1024, 512);

    ez_kernel<<<3072, 256, 0, stream>>>(qev, U1T, Zb);
    es_kernel<<<384, 256, 0, stream>>>(Zb, mSb, lIb);
    att_kernel<<<3072, 256, 0, stream>>>(qev, kvb, Zb, mSb, lIb, adp, U2bT, aout);

    gemm_bt<1><<<dim3(384, 4), 256, 0, stream>>>(aout, Wob, bo, d_out, 49152, 512, 512);
}

// Round 3
// 477.884 us; speedup vs baseline: 1.1212x; 1.1212x over previous
//
#include <hip/hip_runtime.h>

// ---------------------------------------------------------------------------
// AttentionLayer_Spa — MI355X bf16-MFMA pipeline
//   B=4 T=12 N=1024 C=128 D=512 H=8 hd=64 S=60, BT=48
// R2: att restructured: V pre-transposed in G2 epilogue (vT), K/U2/V frags
//     direct from global, exa in registers, Ps per-wave-private -> ZERO
//     barriers, LDS 80KB->34.8KB. cvt_x+pool_x fused.
// ---------------------------------------------------------------------------

#define LOG2E 1.44269504088896f

typedef __attribute__((ext_vector_type(4))) float f32x4;
typedef __attribute__((ext_vector_type(8))) short bf16x8;

__device__ __forceinline__ unsigned short f2bf(float f) {
    union { float f; unsigned u; } v; v.f = f;
    unsigned r = (v.u + 0x7fffu + ((v.u >> 16) & 1u)) >> 16;
    return (unsigned short)r;
}
__device__ __forceinline__ float bf2f(unsigned short h) {
    union { unsigned u; float f; } v; v.u = ((unsigned)h) << 16;
    return v.f;
}

// ---------------------------------------------------------------------------
// K0a: weight/bias conversion (unchanged from R1).
// ---------------------------------------------------------------------------
__global__ void cvt_w(const float* __restrict__ Wq, const float* __restrict__ Wk,
                      const float* __restrict__ Wv, const float* __restrict__ We,
                      const float* __restrict__ Wo, const float* __restrict__ U1,
                      const float* __restrict__ U2,
                      const float* __restrict__ bq, const float* __restrict__ bk,
                      const float* __restrict__ bv, const float* __restrict__ be,
                      unsigned short* __restrict__ Wqe, unsigned short* __restrict__ Wkv,
                      unsigned short* __restrict__ Wob, unsigned short* __restrict__ U1T,
                      unsigned short* __restrict__ U2bT,
                      float* __restrict__ bqe, float* __restrict__ bkv)
{
    int i = blockIdx.x * 256 + threadIdx.x;
    if (i < 524288) {
        int r = i >> 9;
        float v = (r < 512) ? Wq[i] : We[i - 262144];
        Wqe[i] = f2bf(v);
    } else if (i < 1048576) {
        int j = i - 524288; int r = j >> 9;
        float v = (r < 512) ? Wk[j] : Wv[j - 262144];
        Wkv[j] = f2bf(v);
    } else if (i < 1310720) {
        int j = i - 1048576;
        Wob[j] = f2bf(Wo[j]);
    } else if (i < 1314816) {
        int j = i - 1310720; int s = j >> 6, k = j & 63;
        U1T[j] = (s < 60) ? f2bf(U1[k * 60 + s]) : (unsigned short)0;
    } else if (i < 1318912) {
        int j = i - 1314816; int d = j >> 6, s = j & 63;
        U2bT[j] = (s < 60) ? f2bf(U2[s * 64 + d] * 0.5f) : (unsigned short)0;
    } else if (i < 1319936) {
        int j = i - 1318912;
        bqe[j] = (j < 512) ? bq[j] : be[j - 512];
    } else if (i < 1320960) {
        int j = i - 1319936;
        bkv[j] = (j < 512) ? bk[j] : bv[j - 512];
    }
}

// ---------------------------------------------------------------------------
// K0b: fused x->bf16 + pooled-x->bf16. One read of x (100MB) instead of two.
// thread = (bt, c, d4): 8 float4 loads (pool rows), 8 ushort4 xb writes,
// 1 ushort4 xpb write.  786432 threads, grid 3072.
// ---------------------------------------------------------------------------
__global__ void cvt_pool(const float* __restrict__ x, unsigned short* __restrict__ xb,
                         unsigned short* __restrict__ xpb)
{
    int i = blockIdx.x * 256 + threadIdx.x;   // < 786432
    int d4 = i & 127;
    int btc = i >> 7;                          // bt*128 + c
    int bt = btc >> 7, c = btc & 127;
    long base = ((long)(bt * 1024 + c * 8)) * 128 + d4;
    const float4* src = (const float4*)x + base;
    ushort4* dst = (ushort4*)xb + base;
    float sx = 0.f, sy = 0.f, sz = 0.f, sw = 0.f;
#pragma unroll
    for (int j = 0; j < 8; j++) {
        float4 v = src[(long)j * 128];
        sx += v.x; sy += v.y; sz += v.z; sw += v.w;
        ushort4 o;
        o.x = f2bf(v.x); o.y = f2bf(v.y); o.z = f2bf(v.z); o.w = f2bf(v.w);
        dst[(long)j * 128] = o;
    }
    ushort4 p;
    p.x = f2bf(sx * 0.125f); p.y = f2bf(sy * 0.125f);
    p.z = f2bf(sz * 0.125f); p.w = f2bf(sw * 0.125f);
    ((ushort4*)xpb)[(long)btc * 128 + d4] = p;
}

// ---------------------------------------------------------------------------
// GEMM: C(MxN) = A(MxK) @ W(NxK)^T + bias[N].  bf16 in, bf16 or fp32 out.
// 128x128 tile, BK=32, 4 waves (2x2 of 64x64), 16x16x32 bf16 MFMA.
// ---------------------------------------------------------------------------
template <int OUTF32>
__global__ __launch_bounds__(256, 2) void gemm_bt(
    const unsigned short* __restrict__ A, const unsigned short* __restrict__ W,
    const float* __restrict__ bias, void* __restrict__ Cout,
    int M, int N, int K)
{
    __shared__ __attribute__((aligned(16))) unsigned short As[128 * 32];
    __shared__ __attribute__((aligned(16))) unsigned short Bs[128 * 32];
    const int tid = threadIdx.x;
    const int wave = tid >> 6, lane = tid & 63;
    const int quad = lane >> 4, l16 = lane & 15;
    const int m0 = blockIdx.x * 128, n0 = blockIdx.y * 128;
    const int wm = (wave & 1) * 64, wn = (wave >> 1) * 64;

    f32x4 acc[4][4];
#pragma unroll
    for (int i = 0; i < 4; i++)
#pragma unroll
        for (int j = 0; j < 4; j++) acc[i][j] = (f32x4){0.f, 0.f, 0.f, 0.f};

    const int c0 = tid, c1 = tid + 256;
    const int r0 = c0 >> 2, kc0 = (c0 & 3) * 8;
    const int r1 = c1 >> 2, kc1 = (c1 & 3) * 8;

    for (int k0 = 0; k0 < K; k0 += 32) {
        int4 a0 = *(const int4*)(A + (long)(m0 + r0) * K + k0 + kc0);
        int4 a1 = *(const int4*)(A + (long)(m0 + r1) * K + k0 + kc1);
        int4 b0 = *(const int4*)(W + (long)(n0 + r0) * K + k0 + kc0);
        int4 b1 = *(const int4*)(W + (long)(n0 + r1) * K + k0 + kc1);
        __syncthreads();
        *(int4*)&As[c0 * 8] = a0; *(int4*)&As[c1 * 8] = a1;
        *(int4*)&Bs[c0 * 8] = b0; *(int4*)&Bs[c1 * 8] = b1;
        __syncthreads();
        bf16x8 af[4], bfr[4];
#pragma unroll
        for (int t = 0; t < 4; t++)
            af[t] = *(const bf16x8*)&As[(wm + t * 16 + l16) * 32 + quad * 8];
#pragma unroll
        for (int t = 0; t < 4; t++)
            bfr[t] = *(const bf16x8*)&Bs[(wn + t * 16 + l16) * 32 + quad * 8];
#pragma unroll
        for (int tm = 0; tm < 4; tm++)
#pragma unroll
            for (int tn = 0; tn < 4; tn++)
                acc[tm][tn] = __builtin_amdgcn_mfma_f32_16x16x32_bf16(
                    af[tm], bfr[tn], acc[tm][tn], 0, 0, 0);
    }

#pragma unroll
    for (int tm = 0; tm < 4; tm++)
#pragma unroll
        for (int tn = 0; tn < 4; tn++) {
            int cc = n0 + wn + tn * 16 + l16;
            float bv = bias[cc];
#pragma unroll
            for (int r = 0; r < 4; r++) {
                int rr = m0 + wm + tm * 16 + quad * 4 + r;
                float v = acc[tm][tn][r] + bv;
                if (OUTF32) ((float*)Cout)[(long)rr * N + cc] = v;
                else        ((unsigned short*)Cout)[(long)rr * N + cc] = f2bf(v);
            }
        }
}

// ---------------------------------------------------------------------------
// G2: kv = xp @ Wkv^T + bkv.  K half (cols<512) -> kvK row-major (stride 512).
// V half -> vT[(bt*8+h)*64 + d][c] (pre-transposed for att B-fragments).
// M=6144, N=1024, K=512. grid (48, 8).
// ---------------------------------------------------------------------------
__global__ __launch_bounds__(256, 2) void g2_kv(
    const unsigned short* __restrict__ A, const unsigned short* __restrict__ W,
    const float* __restrict__ bias, unsigned short* __restrict__ kvK,
    unsigned short* __restrict__ vT)
{
    const int M = 6144, N = 1024, K = 512;
    __shared__ __attribute__((aligned(16))) unsigned short As[128 * 32];
    __shared__ __attribute__((aligned(16))) unsigned short Bs[128 * 32];
    const int tid = threadIdx.x;
    const int wave = tid >> 6, lane = tid & 63;
    const int quad = lane >> 4, l16 = lane & 15;
    const int m0 = blockIdx.x * 128, n0 = blockIdx.y * 128;
    const int wm = (wave & 1) * 64, wn = (wave >> 1) * 64;
    (void)M;

    f32x4 acc[4][4];
#pragma unroll
    for (int i = 0; i < 4; i++)
#pragma unroll
        for (int j = 0; j < 4; j++) acc[i][j] = (f32x4){0.f, 0.f, 0.f, 0.f};

    const int c0 = tid, c1 = tid + 256;
    const int r0 = c0 >> 2, kc0 = (c0 & 3) * 8;
    const int r1 = c1 >> 2, kc1 = (c1 & 3) * 8;

    for (int k0 = 0; k0 < K; k0 += 32) {
        int4 a0 = *(const int4*)(A + (long)(m0 + r0) * K + k0 + kc0);
        int4 a1 = *(const int4*)(A + (long)(m0 + r1) * K + k0 + kc1);
        int4 b0 = *(const int4*)(W + (long)(n0 + r0) * K + k0 + kc0);
        int4 b1 = *(const int4*)(W + (long)(n0 + r1) * K + k0 + kc1);
        __syncthreads();
        *(int4*)&As[c0 * 8] = a0; *(int4*)&As[c1 * 8] = a1;
        *(int4*)&Bs[c0 * 8] = b0; *(int4*)&Bs[c1 * 8] = b1;
        __syncthreads();
        bf16x8 af[4], bfr[4];
#pragma unroll
        for (int t = 0; t < 4; t++)
            af[t] = *(const bf16x8*)&As[(wm + t * 16 + l16) * 32 + quad * 8];
#pragma unroll
        for (int t = 0; t < 4; t++)
            bfr[t] = *(const bf16x8*)&Bs[(wn + t * 16 + l16) * 32 + quad * 8];
#pragma unroll
        for (int tm = 0; tm < 4; tm++)
#pragma unroll
            for (int tn = 0; tn < 4; tn++)
                acc[tm][tn] = __builtin_amdgcn_mfma_f32_16x16x32_bf16(
                    af[tm], bfr[tn], acc[tm][tn], 0, 0, 0);
    }

#pragma unroll
    for (int tm = 0; tm < 4; tm++)
#pragma unroll
        for (int tn = 0; tn < 4; tn++) {
            int cc = n0 + wn + tn * 16 + l16;
            float bv = bias[cc];
            int rrb = m0 + wm + tm * 16 + quad * 4;
            if (cc < 512) {
#pragma unroll
                for (int r = 0; r < 4; r++)
                    kvK[(long)(rrb + r) * 512 + cc] = f2bf(acc[tm][tn][r] + bv);
            } else {
                int hh = (cc - 512) >> 6, dd = (cc - 512) & 63;
                int btv = rrb >> 7, cv = rrb & 127;   // 4 consecutive rr, same bt
                ushort4 o;
                o.x = f2bf(acc[tm][tn][0] + bv);
                o.y = f2bf(acc[tm][tn][1] + bv);
                o.z = f2bf(acc[tm][tn][2] + bv);
                o.w = f2bf(acc[tm][tn][3] + bv);
                *(ushort4*)(vT + ((long)(btv * 8 + hh) * 64 + dd) * 128 + cv) = o;
            }
        }
}

// ---------------------------------------------------------------------------
// EZ: Z[(bt*8+h)*1024+n][s] = ev[bt,n,h*64:...] @ U1  (bf16 out, s<60)
// ---------------------------------------------------------------------------
__global__ __launch_bounds__(256, 2) void ez_kernel(
    const unsigned short* __restrict__ qev, const unsigned short* __restrict__ U1T,
    unsigned short* __restrict__ Z)
{
    __shared__ __attribute__((aligned(16))) unsigned short evs[128 * 72];
    __shared__ __attribute__((aligned(16))) unsigned short u1s[64 * 72];
    int tid = threadIdx.x, bx = blockIdx.x;
    int bt = bx >> 6, h = (bx >> 3) & 7, nb = bx & 7;
    int wave = tid >> 6, lane = tid & 63, quad = lane >> 4, l16 = lane & 15;

#pragma unroll
    for (int i = 0; i < 4; i++) {
        int c = tid + i * 256; int row = c >> 3, kc = (c & 7) * 8;
        *(int4*)&evs[row * 72 + kc] =
            *(const int4*)(qev + ((long)(bt * 1024 + nb * 128 + row)) * 1024 + 512 + h * 64 + kc);
    }
#pragma unroll
    for (int i = 0; i < 2; i++) {
        int c = tid + i * 256; int row = c >> 3, kc = (c & 7) * 8;
        *(int4*)&u1s[row * 72 + kc] = *(const int4*)(U1T + row * 64 + kc);
    }
    __syncthreads();

    f32x4 acc[2][4];
#pragma unroll
    for (int i = 0; i < 2; i++)
#pragma unroll
        for (int t = 0; t < 4; t++) acc[i][t] = (f32x4){0.f, 0.f, 0.f, 0.f};

#pragma unroll
    for (int kt = 0; kt < 2; kt++) {
        bf16x8 a[2], b[4];
#pragma unroll
        for (int i = 0; i < 2; i++)
            a[i] = *(const bf16x8*)&evs[((wave * 2 + i) * 16 + l16) * 72 + kt * 32 + quad * 8];
#pragma unroll
        for (int t = 0; t < 4; t++)
            b[t] = *(const bf16x8*)&u1s[(t * 16 + l16) * 72 + kt * 32 + quad * 8];
#pragma unroll
        for (int i = 0; i < 2; i++)
#pragma unroll
            for (int t = 0; t < 4; t++)
                acc[i][t] = __builtin_amdgcn_mfma_f32_16x16x32_bf16(a[i], b[t], acc[i][t], 0, 0, 0);
    }

    long zb = (long)(bt * 8 + h) * 1024 + nb * 128;
#pragma unroll
    for (int i = 0; i < 2; i++)
#pragma unroll
        for (int t = 0; t < 4; t++) {
            int s = t * 16 + l16;
            if (s < 60) {
#pragma unroll
                for (int r = 0; r < 4; r++) {
                    int rr = (wave * 2 + i) * 16 + quad * 4 + r;
                    Z[(zb + rr) * 60 + s] = f2bf(acc[i][t][r]);
                }
            }
        }
}

// ---------------------------------------------------------------------------
// ES: per (bt,h): column softmax stats over n for s<60.
// ---------------------------------------------------------------------------
__global__ __launch_bounds__(256, 2) void es_kernel(
    const unsigned short* __restrict__ Z, float* __restrict__ mS, float* __restrict__ lSinv)
{
    __shared__ float ms[4][64];
    __shared__ float ls[4][64];
    int tid = threadIdx.x;
    int s = tid & 63, g = tid >> 6;
    long zb = (long)blockIdx.x * 1024 * 60;
    float m = -1e30f, l = 0.f;
    if (s < 60) {
        for (int r = 0; r < 256; r++) {
            float z = bf2f(Z[zb + (long)(g * 256 + r) * 60 + s]);
            float nm = fmaxf(m, z);
            l = l * exp2f((m - nm) * LOG2E) + exp2f((z - nm) * LOG2E);
            m = nm;
        }
    }
    ms[g][s] = m; ls[g][s] = l;
    __syncthreads();
    if (tid < 60) {
        float M = fmaxf(fmaxf(ms[0][tid], ms[1][tid]), fmaxf(ms[2][tid], ms[3][tid]));
        float L = 0.f;
#pragma unroll
        for (int gg = 0; gg < 4; gg++) L += ls[gg][tid] * exp2f((ms[gg][tid] - M) * LOG2E);
        mS[blockIdx.x * 60 + tid] = M;
        lSinv[blockIdx.x * 60 + tid] = 1.0f / L;
    }
}

// ---------------------------------------------------------------------------
// ATT v2: per (bt,h,nb): 128 q-rows, 256 threads, NO barriers.
//   K/V/U2 fragments direct from global (L2-resident); exa in registers;
//   Ps (C->A layout round-trip) per-wave-private in LDS (34.8KB).
// ---------------------------------------------------------------------------
__global__ __launch_bounds__(256, 3) void att_kernel(
    const unsigned short* __restrict__ qev, const unsigned short* __restrict__ kvK,
    const unsigned short* __restrict__ vT, const unsigned short* __restrict__ Z,
    const float* __restrict__ mS, const float* __restrict__ lI,
    const float* __restrict__ adp, const unsigned short* __restrict__ U2bT,
    unsigned short* __restrict__ attn_out)
{
    __shared__ __attribute__((aligned(16))) unsigned short Ps[128 * 136];

    int tid = threadIdx.x, bx = blockIdx.x;
    int bt = bx >> 6, h = (bx >> 3) & 7, nb = bx & 7;
    int wave = tid >> 6, lane = tid & 63, quad = lane >> 4, l16 = lane & 15;
    int n0 = nb * 128;
    const int g = bt * 8 + h;
    const long qrow0 = (long)bt * 1024 + n0;

    // --- score: S = q @ k^T ---
    f32x4 sc[2][8];
#pragma unroll
    for (int i = 0; i < 2; i++)
#pragma unroll
        for (int t = 0; t < 8; t++) sc[i][t] = (f32x4){0.f, 0.f, 0.f, 0.f};

#pragma unroll
    for (int kt = 0; kt < 2; kt++) {
        bf16x8 a[2];
#pragma unroll
        for (int i = 0; i < 2; i++)
            a[i] = *(const bf16x8*)(qev + (qrow0 + (wave * 2 + i) * 16 + l16) * 1024
                                    + h * 64 + kt * 32 + quad * 8);
#pragma unroll
        for (int tn = 0; tn < 8; tn++) {
            bf16x8 b = *(const bf16x8*)(kvK + (long)(bt * 128 + tn * 16 + l16) * 512
                                        + h * 64 + kt * 32 + quad * 8);
#pragma unroll
            for (int i = 0; i < 2; i++)
                sc[i][tn] = __builtin_amdgcn_mfma_f32_16x16x32_bf16(a[i], b, sc[i][tn], 0, 0, 0);
        }
    }

    // --- softmax over 128 cols; write P to per-wave-private Ps rows ---
#pragma unroll
    for (int i = 0; i < 2; i++) {
#pragma unroll
        for (int tn = 0; tn < 8; tn++)
#pragma unroll
            for (int r = 0; r < 4; r++) {
                int rr = (wave * 2 + i) * 16 + quad * 4 + r;
                sc[i][tn][r] = sc[i][tn][r] * 0.125f + adp[(n0 + rr) * 128 + tn * 16 + l16];
            }
        float rmax[4], rsum[4];
#pragma unroll
        for (int r = 0; r < 4; r++) {
            float m = sc[i][0][r];
#pragma unroll
            for (int tn = 1; tn < 8; tn++) m = fmaxf(m, sc[i][tn][r]);
#pragma unroll
            for (int d = 1; d < 16; d <<= 1) m = fmaxf(m, __shfl_xor(m, d, 64));
            rmax[r] = m; rsum[r] = 0.f;
        }
#pragma unroll
        for (int tn = 0; tn < 8; tn++)
#pragma unroll
            for (int r = 0; r < 4; r++) {
                float p = exp2f((sc[i][tn][r] - rmax[r]) * LOG2E);
                sc[i][tn][r] = p; rsum[r] += p;
            }
#pragma unroll
        for (int r = 0; r < 4; r++) {
#pragma unroll
            for (int d = 1; d < 16; d <<= 1) rsum[r] += __shfl_xor(rsum[r], d, 64);
            rsum[r] = 1.0f / rsum[r];
        }
#pragma unroll
        for (int tn = 0; tn < 8; tn++)
#pragma unroll
            for (int r = 0; r < 4; r++) {
                int rr = (wave * 2 + i) * 16 + quad * 4 + r;
                Ps[rr * 136 + tn * 16 + l16] = f2bf(sc[i][tn][r] * rsum[r]);
            }
    }
    // no barrier: wave w wrote rows [32w, 32w+32) and reads only those below.

    // --- out = P @ vh (K=128) ---
    f32x4 oc[2][4];
#pragma unroll
    for (int i = 0; i < 2; i++)
#pragma unroll
        for (int t = 0; t < 4; t++) oc[i][t] = (f32x4){0.f, 0.f, 0.f, 0.f};

#pragma unroll
    for (int kt = 0; kt < 4; kt++) {
        bf16x8 a[2];
#pragma unroll
        for (int i = 0; i < 2; i++)
            a[i] = *(const bf16x8*)&Ps[((wave * 2 + i) * 16 + l16) * 136 + kt * 32 + quad * 8];
#pragma unroll
        for (int tn = 0; tn < 4; tn++) {
            bf16x8 b = *(const bf16x8*)(vT + ((long)g * 64 + tn * 16 + l16) * 128
                                        + kt * 32 + quad * 8);
#pragma unroll
            for (int i = 0; i < 2; i++)
                oc[i][tn] = __builtin_amdgcn_mfma_f32_16x16x32_bf16(a[i], b, oc[i][tn], 0, 0, 0);
        }
    }

    // --- += exa @ U2b (K=64), exa built in registers from Z/mS/lI ---
#pragma unroll
    for (int kt = 0; kt < 2; kt++) {
        int sb = kt * 32 + quad * 8;
        float4 ma = *(const float4*)(mS + (long)g * 60 + sb);
        float4 mb2 = *(const float4*)(mS + (long)g * 60 + sb + 4);
        float4 la = *(const float4*)(lI + (long)g * 60 + sb);
        float4 lb2 = *(const float4*)(lI + (long)g * 60 + sb + 4);
        float mv[8] = {ma.x, ma.y, ma.z, ma.w, mb2.x, mb2.y, mb2.z, mb2.w};
        float lv[8] = {la.x, la.y, la.z, la.w, lb2.x, lb2.y, lb2.z, lb2.w};
        bf16x8 ea[2];
#pragma unroll
        for (int i = 0; i < 2; i++) {
            int row = (wave * 2 + i) * 16 + l16;
            const unsigned short* zp = Z + ((long)g * 1024 + n0 + row) * 60 + sb;
            uint2 z0 = *(const uint2*)zp;
            uint2 z1 = *(const uint2*)(zp + 4);
            unsigned zz[4] = {z0.x, z0.y, z1.x, z1.y};
            unsigned short es_[8];
#pragma unroll
            for (int j = 0; j < 8; j++) {
                unsigned short zh = (unsigned short)((zz[j >> 1] >> ((j & 1) * 16)) & 0xffff);
                float e = (sb + j < 60)
                    ? exp2f((bf2f(zh) - mv[j]) * LOG2E) * lv[j] : 0.f;
                es_[j] = f2bf(e);
            }
            ea[i] = *(bf16x8*)es_;
        }
#pragma unroll
        for (int tn = 0; tn < 4; tn++) {
            bf16x8 b = *(const bf16x8*)(U2bT + (tn * 16 + l16) * 64 + sb);
#pragma unroll
            for (int i = 0; i < 2; i++)
                oc[i][tn] = __builtin_amdgcn_mfma_f32_16x16x32_bf16(ea[i], b, oc[i][tn], 0, 0, 0);
        }
    }

    // --- epilogue: + ev, write merged-head attn_out (bf16) ---
#pragma unroll
    for (int i = 0; i < 2; i++)
#pragma unroll
        for (int tn = 0; tn < 4; tn++)
#pragma unroll
            for (int r = 0; r < 4; r++) {
                int rr = (wave * 2 + i) * 16 + quad * 4 + r;
                int cc = tn * 16 + l16;
                float ev = bf2f(qev[(qrow0 + rr) * 1024 + 512 + h * 64 + cc]);
                attn_out[(qrow0 + rr) * 512 + h * 64 + cc] = f2bf(oc[i][tn][r] + ev);
            }
}

// ---------------------------------------------------------------------------
// launch
// ---------------------------------------------------------------------------
extern "C" void kernel_launch(void* const* d_in, const int* in_sizes, int n_in,
                              void* d_out, int out_size, void* d_ws, size_t ws_size,
                              hipStream_t stream)
{
    const float* x   = (const float*)d_in[0];
    const float* Wq  = (const float*)d_in[1];
    const float* bq  = (const float*)d_in[2];
    const float* Wk  = (const float*)d_in[3];
    const float* bk  = (const float*)d_in[4];
    const float* Wv  = (const float*)d_in[5];
    const float* bv  = (const float*)d_in[6];
    const float* We  = (const float*)d_in[7];
    const float* be  = (const float*)d_in[8];
    const float* Wo  = (const float*)d_in[9];
    const float* bo  = (const float*)d_in[10];
    const float* adp = (const float*)d_in[11];
    const float* U1  = (const float*)d_in[12];
    const float* U2  = (const float*)d_in[13];

    char* ws = (char*)d_ws;
    unsigned short* xb   = (unsigned short*)(ws + 0);          // 50,331,648 B
    unsigned short* aout = xb;                                 // alias: xb dead after G1
    unsigned short* xpb  = (unsigned short*)(ws + 50331648);   //  6,291,456
    unsigned short* qev  = (unsigned short*)(ws + 56623104);   // 100,663,296
    unsigned short* kvK  = (unsigned short*)(ws + 157286400);  //  6,291,456 (6144x512)
    unsigned short* vT   = (unsigned short*)(ws + 163577856);  //  6,291,456 (384x64x128)
    unsigned short* Zb   = (unsigned short*)(ws + 169869312);  // 47,185,920
    unsigned short* Wqe  = (unsigned short*)(ws + 217055232);  //  1,048,576
    unsigned short* Wkv  = (unsigned short*)(ws + 218103808);  //  1,048,576
    unsigned short* Wob  = (unsigned short*)(ws + 219152384);  //    524,288
    unsigned short* U1T  = (unsigned short*)(ws + 219676672);  //      8,192
    unsigned short* U2bT = (unsigned short*)(ws + 219684864);  //      8,192
    float*          mSb  = (float*)(ws + 219693056);           //     92,160
    float*          lIb  = (float*)(ws + 219785216);           //     92,160
    float*          bqe  = (float*)(ws + 219877376);           //      4,096 (also pads lIb tail reads)
    float*          bkv  = (float*)(ws + 219881472);           //      4,096
    // total: 219,885,568 B (same footprint that passed in R2)

    cvt_w<<<5160, 256, 0, stream>>>(Wq, Wk, Wv, We, Wo, U1, U2, bq, bk, bv, be,
                                    Wqe, Wkv, Wob, U1T, U2bT, bqe, bkv);
    cvt_pool<<<3072, 256, 0, stream>>>(x, xb, xpb);

    gemm_bt<0><<<dim3(384, 8), 256, 0, stream>>>(xb,  Wqe, bqe, (void*)qev, 49152, 1024, 512);
    g2_kv<<<dim3(48, 8), 256, 0, stream>>>(xpb, Wkv, bkv, kvK, vT);

    ez_kernel<<<3072, 256, 0, stream>>>(qev, U1T, Zb);
    es_kernel<<<384, 256, 0, stream>>>(Zb, mSb, lIb);
    att_kernel<<<3072, 256, 0, stream>>>(qev, kvK, vT, Zb, mSb, lIb, adp, U2bT, aout);

    gemm_bt<1><<<dim3(384, 4), 256, 0, stream>>>(aout, Wob, bo, d_out, 49152, 512, 512);
}